// Round 1
// baseline (301.896 us; speedup 1.0000x reference)
//
#include <hip/hip_runtime.h>
#include <cstddef>

// Problem constants (fixed by the reference):
//   B=16, h=8, Ch=32, H=W=56, N=3136
//   heads 0-1  -> 3x3 dwconv (w3,b3), channel base hh*32
//   heads 2-4  -> 5x5 dwconv (w5,b5), channel base hh*32-64
//   heads 5-7  -> 7x7 dwconv (w7,b7), channel base hh*32-160
// out[b][n][hh*32+ch] = q[b][hh][n][ch] * (dwconv(v)[b][hh][n][ch])

#define BH 16
#define NH 8
#define CH 32
#define HW 56
#define NN (HW*HW)

template<int K>
__device__ __forceinline__ void run_head(
    const float* __restrict__ q, const float* __restrict__ v,
    const float* __restrict__ w, const float* __restrict__ bias,
    float* __restrict__ out, int b, int hh, int y0, int cbase,
    float* __restrict__ w_lds)
{
    constexpr int P = K / 2;
    constexpr int NR = 7 + K - 1;      // sliding-window width per dy row
    const int t = threadIdx.x;

    // Stage weights into LDS, layout [tap][c] (c = 0..31 within this head).
    // Global layout is w[c_local][0][ky][kx] with c stride K*K.
    const int nw = K * K * CH;
    for (int i = t; i < nw; i += 256) {
        int tap = i >> 5, c = i & 31;
        w_lds[tap * CH + c] = w[(cbase + c) * (K * K) + tap];
    }
    __syncthreads();

    const int y    = y0 + (t >> 6);    // 4 rows per block
    const int lane = t & 63;
    const int xseg = lane >> 3;        // 0..7  -> x0 = xseg*7
    const int chq  = lane & 7;         // 0..7  -> ch = chq*4
    const int x0   = xseg * 7;
    const int ch   = chq * 4;

    const size_t plane = ((size_t)b * NH + hh) * (size_t)NN * CH;
    const float* vb = v + plane;
    const float* qb = q + plane;

    float4 bias4 = *(const float4*)(bias + cbase + ch);
    float4 acc[7];
#pragma unroll
    for (int i = 0; i < 7; ++i) acc[i] = bias4;

#pragma unroll
    for (int dy = 0; dy < K; ++dy) {
        const int yy = y + dy - P;
        const bool rok = ((unsigned)yy < (unsigned)HW);
        float4 r[NR];
#pragma unroll
        for (int j = 0; j < NR; ++j) {
            const int xx = x0 + j - P;
            float4 val; val.x = 0.f; val.y = 0.f; val.z = 0.f; val.w = 0.f;
            if (rok && (unsigned)xx < (unsigned)HW) {
                val = *(const float4*)(vb + ((size_t)yy * HW + xx) * CH + ch);
            }
            r[j] = val;
        }
#pragma unroll
        for (int dx = 0; dx < K; ++dx) {
            const float4 w4 = *(const float4*)(w_lds + (dy * K + dx) * CH + ch);
#pragma unroll
            for (int i = 0; i < 7; ++i) {
                acc[i].x += r[i + dx].x * w4.x;
                acc[i].y += r[i + dx].y * w4.y;
                acc[i].z += r[i + dx].z * w4.z;
                acc[i].w += r[i + dx].w * w4.w;
            }
        }
    }

    // ev = q * conv_v; write out[b][n][hh*32+ch]
#pragma unroll
    for (int i = 0; i < 7; ++i) {
        const int n = y * HW + x0 + i;
        const float4 q4 = *(const float4*)(qb + (size_t)n * CH + ch);
        float4 o;
        o.x = acc[i].x * q4.x;
        o.y = acc[i].y * q4.y;
        o.z = acc[i].z * q4.z;
        o.w = acc[i].w * q4.w;
        *(float4*)(out + ((size_t)b * NN + n) * (NH * CH) + hh * CH + ch) = o;
    }
}

__global__ __launch_bounds__(256)
void clusterformer_fused(const float* __restrict__ q, const float* __restrict__ v,
                         const float* __restrict__ w3, const float* __restrict__ b3,
                         const float* __restrict__ w5, const float* __restrict__ b5,
                         const float* __restrict__ w7, const float* __restrict__ b7,
                         float* __restrict__ out)
{
    __shared__ float w_lds[49 * CH];   // max K=7: 49 taps * 32 ch = 6272 B
    const int bid = blockIdx.x;
    const int yg = bid % 14;           // 14 groups of 4 rows
    const int hh = (bid / 14) % NH;
    const int b  = bid / (14 * NH);
    const int y0 = yg * 4;

    if (hh < 2)      run_head<3>(q, v, w3, b3, out, b, hh, y0, hh * 32,       w_lds);
    else if (hh < 5) run_head<5>(q, v, w5, b5, out, b, hh, y0, hh * 32 - 64,  w_lds);
    else             run_head<7>(q, v, w7, b7, out, b, hh, y0, hh * 32 - 160, w_lds);
}

extern "C" void kernel_launch(void* const* d_in, const int* in_sizes, int n_in,
                              void* d_out, int out_size, void* d_ws, size_t ws_size,
                              hipStream_t stream) {
    const float* q  = (const float*)d_in[0];
    const float* v  = (const float*)d_in[1];
    const float* w3 = (const float*)d_in[2];
    const float* b3 = (const float*)d_in[3];
    const float* w5 = (const float*)d_in[4];
    const float* b5 = (const float*)d_in[5];
    const float* w7 = (const float*)d_in[6];
    const float* b7 = (const float*)d_in[7];
    float* out = (float*)d_out;

    const int grid = BH * NH * 14;     // 1792 blocks
    clusterformer_fused<<<grid, 256, 0, stream>>>(q, v, w3, b3, w5, b5, w7, b7, out);
}

// Round 2
// 182.522 us; speedup vs baseline: 1.6540x; 1.6540x over previous
//
#include <hip/hip_runtime.h>
#include <cstddef>

// Problem constants (fixed by the reference):
//   B=16, h=8, Ch=32, H=W=56, N=3136
//   heads 0-1  -> 3x3 dwconv (w3,b3), channel base hh*32
//   heads 2-4  -> 5x5 dwconv (w5,b5), channel base hh*32-64
//   heads 5-7  -> 7x7 dwconv (w7,b7), channel base hh*32-160
// out[b][n][hh*32+ch] = q[b][hh][n][ch] * (dwconv(v)[b][hh][n][ch])

#define BH 16
#define NH 8
#define CH 32
#define HW 56
#define NN (HW*HW)

template<int K>
__device__ __forceinline__ void run_head(
    const float* __restrict__ q, const float* __restrict__ v,
    const float* __restrict__ w, const float* __restrict__ bias,
    float* __restrict__ out, int b, int hh, int y0, int cbase,
    float* __restrict__ w_lds)
{
    constexpr int P = K / 2;
    constexpr int NR = 7 + K - 1;      // sliding-window width per dy row
    const int t = threadIdx.x;

    // Stage weights into LDS, layout [tap][c] (c = 0..31 within this head).
    const int nw = K * K * CH;
    for (int i = t; i < nw; i += 256) {
        int tap = i >> 5, c = i & 31;
        w_lds[tap * CH + c] = w[(cbase + c) * (K * K) + tap];
    }
    __syncthreads();

    const int y    = y0 + (t >> 6);    // 4 rows per block, 1 row per wave
    const int lane = t & 63;
    const int xseg = lane >> 3;        // 0..7  -> x0 = xseg*7
    const int chq  = lane & 7;         // 0..7  -> ch = chq*4
    const int x0   = xseg * 7;
    const int ch   = chq * 4;

    const size_t plane = ((size_t)b * NH + hh) * (size_t)NN * CH;
    const float* vb = v + plane;
    const float* qb = q + plane;

    // x-dimension masks and clamped column offsets are dy-invariant: hoist.
    float xmask[NR];
    int   xoff[NR];
#pragma unroll
    for (int j = 0; j < NR; ++j) {
        const int xx = x0 + j - P;
        xmask[j] = ((unsigned)xx < (unsigned)HW) ? 1.f : 0.f;
        const int xxc = xx < 0 ? 0 : (xx > HW - 1 ? HW - 1 : xx);
        xoff[j] = xxc * CH;
    }

    float4 bias4 = *(const float4*)(bias + cbase + ch);
    float4 acc[7];
#pragma unroll
    for (int i = 0; i < 7; ++i) acc[i] = bias4;

#pragma unroll
    for (int dy = 0; dy < K; ++dy) {
        const int yy  = y + dy - P;
        const float rmask = ((unsigned)yy < (unsigned)HW) ? 1.f : 0.f;
        const int   yyc   = yy < 0 ? 0 : (yy > HW - 1 ? HW - 1 : yy);
        const float* rowp = vb + (size_t)yyc * (HW * CH) + ch;

        // Unconditional batched loads (clamped addresses, mask-multiplied).
        float4 r[NR];
#pragma unroll
        for (int j = 0; j < NR; ++j) {
            float4 val = *(const float4*)(rowp + xoff[j]);
            const float m = rmask * xmask[j];
            val.x *= m; val.y *= m; val.z *= m; val.w *= m;
            r[j] = val;
        }
#pragma unroll
        for (int dx = 0; dx < K; ++dx) {
            const float4 w4 = *(const float4*)(w_lds + (dy * K + dx) * CH + ch);
#pragma unroll
            for (int i = 0; i < 7; ++i) {
                acc[i].x += r[i + dx].x * w4.x;
                acc[i].y += r[i + dx].y * w4.y;
                acc[i].z += r[i + dx].z * w4.z;
                acc[i].w += r[i + dx].w * w4.w;
            }
        }
    }

    // ev = q * conv_v; write out[b][n][hh*32+ch]
#pragma unroll
    for (int i = 0; i < 7; ++i) {
        const int n = y * HW + x0 + i;
        const float4 q4 = *(const float4*)(qb + (size_t)n * CH + ch);
        float4 o;
        o.x = acc[i].x * q4.x;
        o.y = acc[i].y * q4.y;
        o.z = acc[i].z * q4.z;
        o.w = acc[i].w * q4.w;
        *(float4*)(out + ((size_t)b * NN + n) * (NH * CH) + hh * CH + ch) = o;
    }
}

__global__ __launch_bounds__(256)
void clusterformer_fused(const float* __restrict__ q, const float* __restrict__ v,
                         const float* __restrict__ w3, const float* __restrict__ b3,
                         const float* __restrict__ w5, const float* __restrict__ b5,
                         const float* __restrict__ w7, const float* __restrict__ b7,
                         float* __restrict__ out)
{
    __shared__ float w_lds[49 * CH];   // max K=7: 49 taps * 32 ch = 6272 B
    const int bid = blockIdx.x;
    const int yg = bid % 14;           // 14 groups of 4 rows
    const int hh = (bid / 14) % NH;
    const int b  = bid / (14 * NH);
    const int y0 = yg * 4;

    if (hh < 2)      run_head<3>(q, v, w3, b3, out, b, hh, y0, hh * 32,       w_lds);
    else if (hh < 5) run_head<5>(q, v, w5, b5, out, b, hh, y0, hh * 32 - 64,  w_lds);
    else             run_head<7>(q, v, w7, b7, out, b, hh, y0, hh * 32 - 160, w_lds);
}

extern "C" void kernel_launch(void* const* d_in, const int* in_sizes, int n_in,
                              void* d_out, int out_size, void* d_ws, size_t ws_size,
                              hipStream_t stream) {
    const float* q  = (const float*)d_in[0];
    const float* v  = (const float*)d_in[1];
    const float* w3 = (const float*)d_in[2];
    const float* b3 = (const float*)d_in[3];
    const float* w5 = (const float*)d_in[4];
    const float* b5 = (const float*)d_in[5];
    const float* w7 = (const float*)d_in[6];
    const float* b7 = (const float*)d_in[7];
    float* out = (float*)d_out;

    const int grid = BH * NH * 14;     // 1792 blocks
    clusterformer_fused<<<grid, 256, 0, stream>>>(q, v, w3, b3, w5, b5, w7, b7, out);
}